// Round 13
// baseline (358.419 us; speedup 1.0000x reference)
//
#include <hip/hip_runtime.h>
#include <hip/hip_bf16.h>

#define NROWS 4096
#define NV    204
#define NH    128
#define NG    256

#define HALF_BYTES 16384
#define SMS_OFF    (2 * HALF_BYTES)            // 32768
#define SMS_BYTES  3584                        // 896 floats, v-varying smalls
#define LN_OFF     (SMS_OFF + 2 * SMS_BYTES)   // 39936
#define LDS_BYTES  (LN_OFF + 1024)             // 40960 -> 4 blocks/CU (160KB exactly)

typedef __bf16 bf16x8 __attribute__((ext_vector_type(8)));
typedef float  f32x4  __attribute__((ext_vector_type(4)));

__device__ __forceinline__ float elu_f(float x)  { return x > 0.f ? x : __expf(x) - 1.f; }
__device__ __forceinline__ float sigm_f(float x) { return 1.f / (1.f + __expf(-x)); }

__device__ __forceinline__ void stage16(const void* g, void* l) {
    __builtin_amdgcn_global_load_lds((const __attribute__((address_space(1))) void*)g,
                                     (__attribute__((address_space(3))) void*)l, 16, 0, 0);
}

// 4-wave block stages one 16KB half-tile: wave w moves 4KB (4 x 1KB instrs).
__device__ __forceinline__ void stage_half(const void* src, char* dst, int w, int l) {
    const char* sb = (const char*)src;
    #pragma unroll
    for (int s = 0; s < 4; ++s)
        stage16(sb + (w * 4 + s) * 1024 + l * 16, dst + (w * 4 + s) * 1024);
}

// stage 3584B of smalls: waves 0-2 move 1KB, wave 3 moves 512B (exec-masked).
__device__ __forceinline__ void stage_smalls(const float* src, char* dst, int w, int l) {
    if (w < 3)       stage16((const char*)src + w * 1024 + l * 16, dst + w * 1024);
    else if (l < 32) stage16((const char*)src + 3072 + l * 16,     dst + 3072);
}

// ============ fused setup ============
#define NB_FC2 NV                 // 204
#define NB_GLU (NV * 16)          // 3264
#define NB_SM  NV                 // 204
#define NB_WTS (NROWS / 8)        // 512

__global__ __launch_bounds__(256) void k_setup(
    const float* __restrict__ fc2_w, __bf16* __restrict__ fc2t,
    const float* __restrict__ glu_w, __bf16* __restrict__ glu16,
    const float* __restrict__ fc1_w, const float* __restrict__ fc1_b,
    const float* __restrict__ fc2_b, const float* __restrict__ glu_b,
    const float* __restrict__ skip_w, const float* __restrict__ skip_b,
    float* __restrict__ smalls,
    const float* __restrict__ xs,
    const float* __restrict__ wfc1_w, const float* __restrict__ wfc1_b,
    const float* __restrict__ wfc2_w, const float* __restrict__ wfc2_b,
    const float* __restrict__ wglu_w, const float* __restrict__ wglu_b,
    const float* __restrict__ wln_g,  const float* __restrict__ wln_b,
    float* __restrict__ wts)
{
    __shared__ float tile[64 * 129];
    __shared__ float sx[8][NV];
    __shared__ float sa[8][NH];
    __shared__ float sg[8][2 * NV];

    const int b = blockIdx.x;
    const int t = threadIdx.x;

    if (b < NB_FC2) {
        // fc2t[v][n][k], row n, 16B-chunk ch stored at ch ^ (n&7)
        const int v = b;
        const float* s = fc2_w + (size_t)v * (NH * NH);
        __bf16*      d = fc2t + (size_t)v * (NH * NH);
        for (int h = 0; h < 2; ++h) {
            __syncthreads();
            for (int i = t; i < 64 * 32; i += 256) {
                const int k = i >> 5, n4 = (i & 31) * 4;
                const float4 f = *(const float4*)(s + (h * 64 + k) * 128 + n4);
                tile[k * 129 + n4 + 0] = f.x;
                tile[k * 129 + n4 + 1] = f.y;
                tile[k * 129 + n4 + 2] = f.z;
                tile[k * 129 + n4 + 3] = f.w;
            }
            __syncthreads();
            for (int i = t; i < 128 * 8; i += 256) {
                const int n = i >> 3, kc = (i & 7) * 8;
                bf16x8 o;
                #pragma unroll
                for (int q = 0; q < 8; ++q) o[q] = (__bf16)tile[(kc + q) * 129 + n];
                const int ch  = h * 8 + (i & 7);
                const int chs = ch ^ (n & 7);
                *(bf16x8*)(d + n * 128 + chs * 8) = o;
            }
        }
        return;
    }

    if (b < NB_FC2 + NB_GLU) {
        // glu16: chunk ch of row g stored at ch ^ (g&7)
        const int idx = (b - NB_FC2) * 256 + t;
        const int ch = idx & 15;
        const int g  = (idx >> 4) & 255;
        const int v  = idx >> 12;
        const float* sp = glu_w + (((size_t)v * NG + g) * NH + ch * 8);
        bf16x8 o;
        #pragma unroll
        for (int q = 0; q < 8; ++q) o[q] = (__bf16)sp[q];
        const int dch = ch ^ (g & 7);
        *(bf16x8*)(glu16 + (((size_t)v * NG + g) * NH) + dch * 8) = o;
        return;
    }

    if (b < NB_FC2 + NB_GLU + NB_SM) {
        // smalls[v] (896 floats, stride 1024): fc1_w@0 fc1_b@128 fc2_b@256
        //   glu_b@384(256) skip_w@640 skip_b@768
        const int v = b - (NB_FC2 + NB_GLU);
        float* dst = smalls + (size_t)v * 1024;
        for (int idx = t; idx < 896; idx += 256) {
            float val;
            if      (idx < 128)  val = fc1_w[v * NH + idx];
            else if (idx < 256)  val = fc1_b[v * NH + idx - 128];
            else if (idx < 384)  val = fc2_b[v * NH + idx - 256];
            else if (idx < 640)  val = glu_b[v * NG + idx - 384];
            else if (idx < 768)  val = skip_w[v * NH + idx - 640];
            else                 val = skip_b[v * NH + idx - 768];
            dst[idx] = val;
        }
        return;
    }

    // ---- wts path ----
    const int r0 = (b - NB_FC2 - NB_GLU - NB_SM) * 8;
    const int tr = t >> 5;
    const int tc = t & 31;

    for (int i = t; i < 8 * NV; i += 256) {
        const int r = i / NV, c = i - r * NV;
        sx[r][c] = xs[(size_t)(r0 + r) * NV + c];
    }
    __syncthreads();

    float acc1[4];
    #pragma unroll
    for (int j = 0; j < 4; ++j) acc1[j] = wfc1_b[tc + 32 * j];
    for (int v = 0; v < NV; ++v) {
        const float xv = sx[tr][v];
        #pragma unroll
        for (int j = 0; j < 4; ++j)
            acc1[j] = fmaf(xv, wfc1_w[v * NH + tc + 32 * j], acc1[j]);
    }
    #pragma unroll
    for (int j = 0; j < 4; ++j) sa[tr][tc + 32 * j] = elu_f(acc1[j]);
    __syncthreads();

    float acc2[4];
    #pragma unroll
    for (int j = 0; j < 4; ++j) acc2[j] = wfc2_b[tc + 32 * j];
    for (int h = 0; h < NH; ++h) {
        const float av = sa[tr][h];
        #pragma unroll
        for (int j = 0; j < 4; ++j)
            acc2[j] = fmaf(av, wfc2_w[h * NH + tc + 32 * j], acc2[j]);
    }
    __syncthreads();
    #pragma unroll
    for (int j = 0; j < 4; ++j) sa[tr][tc + 32 * j] = acc2[j];
    __syncthreads();

    float accg[13];
    #pragma unroll
    for (int gi = 0; gi < 12; ++gi) accg[gi] = wglu_b[tc + 32 * gi];
    accg[12] = (tc < 24) ? wglu_b[tc + 384] : 0.f;
    for (int h = 0; h < NH; ++h) {
        const float av = sa[tr][h];
        #pragma unroll
        for (int gi = 0; gi < 12; ++gi)
            accg[gi] = fmaf(av, wglu_w[h * (2 * NV) + tc + 32 * gi], accg[gi]);
        if (tc < 24) accg[12] = fmaf(av, wglu_w[h * (2 * NV) + tc + 384], accg[12]);
    }
    __syncthreads();
    #pragma unroll
    for (int gi = 0; gi < 12; ++gi) sg[tr][tc + 32 * gi] = accg[gi];
    if (tc < 24) sg[tr][tc + 384] = accg[12];
    __syncthreads();

    float tv[7];
    float s1 = 0.f, s2 = 0.f;
    #pragma unroll
    for (int ii = 0; ii < 7; ++ii) {
        const int c = tc + 32 * ii;
        float val = 0.f;
        if (c < NV) {
            const float hg = sg[tr][c] * sigm_f(sg[tr][c + NV]);
            val = sx[tr][c] + hg;
            s1 += val; s2 = fmaf(val, val, s2);
        }
        tv[ii] = val;
    }
    #pragma unroll
    for (int m = 1; m <= 16; m <<= 1) { s1 += __shfl_xor(s1, m); s2 += __shfl_xor(s2, m); }
    const float mu  = s1 * (1.f / 204.f);
    const float var = s2 * (1.f / 204.f) - mu * mu;
    const float rs  = rsqrtf(fmaxf(var, 0.f) + 1e-5f);

    float mx = -1e30f;
    #pragma unroll
    for (int ii = 0; ii < 7; ++ii) {
        const int c = tc + 32 * ii;
        if (c < NV) {
            const float y = fmaf((tv[ii] - mu) * rs, wln_g[c], wln_b[c]);
            tv[ii] = y;
            mx = fmaxf(mx, y);
        }
    }
    #pragma unroll
    for (int m = 1; m <= 16; m <<= 1) mx = fmaxf(mx, __shfl_xor(mx, m));
    float se = 0.f;
    #pragma unroll
    for (int ii = 0; ii < 7; ++ii) {
        const int c = tc + 32 * ii;
        if (c < NV) {
            const float e = __expf(tv[ii] - mx);
            tv[ii] = e;
            se += e;
        }
    }
    #pragma unroll
    for (int m = 1; m <= 16; m <<= 1) se += __shfl_xor(se, m);
    const float inv = 1.f / se;
    #pragma unroll
    for (int ii = 0; ii < 7; ++ii) {
        const int c = tc + 32 * ii;
        if (c < NV) wts[(size_t)(r0 + tr) * NV + c] = tv[ii] * inv;
    }
}

// ============ main kernel: 6-phase ring, vg=16, 4 blocks/CU ============
// R13: grid 1024 (vg=16) fills the 4-blocks/CU capacity that 40KB LDS
// (4x40=160KB exact) + 112 VGPR allow; R12's grid 512 left half the CU
// slots empty (Occupancy 20%). KEEP __launch_bounds__(256,2): (256,4)
// caps VGPR at 64 and re-creates the R7-R11 spill storm (R12 lesson).
__global__ __launch_bounds__(256, 2) void k_main(
    const float*  __restrict__ xs,
    const __bf16* __restrict__ fc2t,    // [v][n][k], chunk^=(n&7) swizzled
    const __bf16* __restrict__ glu16,   // [v][g][k], chunk^=(g&7) swizzled
    const float*  __restrict__ smalls,  // [v][1024f], 896 used
    const float*  __restrict__ ln_g,
    const float*  __restrict__ ln_b,
    const float*  __restrict__ wts,
    float*        __restrict__ out)
{
    __shared__ __align__(16) char lds[LDS_BYTES];

    const int tid = threadIdx.x;
    const int w   = tid >> 6;
    const int l   = tid & 63;
    const int l15 = l & 15;
    const int lg  = l >> 4;
    const int sw7 = l15 & 7;

    const int vg = blockIdx.x & 15;                   // 16 v-groups
    const int m0 = (blockIdx.x >> 4) * 64 + w * 16;   // wave's 16 tokens
    const int nv = (NV - 1 - vg) / 16 + 1;
    const size_t rowoff = (size_t)(m0 + l15) * NV;

    const f32x4 zero4 = {0.f, 0.f, 0.f, 0.f};
    f32x4 acc_out[8];
    #pragma unroll
    for (int j = 0; j < 8; ++j) acc_out[j] = zero4;

    const int  sh0 = l15 + ((lg & 1) << 5);   // redistribute shfl sources (R4-validated)
    const int  sh1 = sh0 + 16;
    const bool rlo = (lg < 2);

    const float* lnS = (const float*)(lds + LN_OFF);

    // ---- prologue: F0(v0) -> slot0, smalls(v0) -> sm0, ln -> static, scalars ----
    float xv, wv, xn, wn;
    {
        stage_half(fc2t + (size_t)vg * (NH * NH), lds, w, l);
        stage_smalls(smalls + (size_t)vg * 1024, lds + SMS_OFF, w, l);
        if (w == 0) {
            const char* p = (l < 32) ? ((const char*)ln_g + l * 16)
                                     : ((const char*)ln_b + (l - 32) * 16);
            stage16(p, lds + LN_OFF);
        }
        xv = xs[rowoff + vg];
        wv = wts[rowoff + vg];
    }

    for (int i = 0; i < nv; ++i) {
        const int v  = vg + 16 * i;
        const int vn = (i + 1 < nv) ? v + 16 : v;   // clamped (redundant last stage)
        const float* sm = (const float*)(lds + SMS_OFF + (i & 1) * SMS_BYTES);
        const __bf16* gluv = glu16 + (size_t)v * (NG * NH);

        // ============ P0: consume F0 (slot0); stage F1 -> slot1 ============
        __syncthreads();
        stage_half(fc2t + (size_t)v * (NH * NH) + 64 * NH, lds + HALF_BYTES, w, l);

        // A1: h1[token l15][k], k = kb*32 + lg*8 + b (B-operand layout)
        bf16x8 a1[4];
        #pragma unroll
        for (int kb = 0; kb < 4; ++kb) {
            const int k0 = kb * 32 + lg * 8;
            const float4 w0 = *(const float4*)(sm + k0);
            const float4 w1 = *(const float4*)(sm + k0 + 4);
            const float4 b0 = *(const float4*)(sm + 128 + k0);
            const float4 b1 = *(const float4*)(sm + 128 + k0 + 4);
            bf16x8 af;
            af[0] = (__bf16)elu_f(fmaf(xv, w0.x, b0.x));
            af[1] = (__bf16)elu_f(fmaf(xv, w0.y, b0.y));
            af[2] = (__bf16)elu_f(fmaf(xv, w0.z, b0.z));
            af[3] = (__bf16)elu_f(fmaf(xv, w0.w, b0.w));
            af[4] = (__bf16)elu_f(fmaf(xv, w1.x, b1.x));
            af[5] = (__bf16)elu_f(fmaf(xv, w1.y, b1.y));
            af[6] = (__bf16)elu_f(fmaf(xv, w1.z, b1.z));
            af[7] = (__bf16)elu_f(fmaf(xv, w1.w, b1.w));
            a1[kb] = af;
        }

        // GEMM1 swapped, j=0..3: lane(l15,lg) reg r = h2[tok l15][j*16+lg*4+r]
        f32x4 h2f[8];
        #pragma unroll
        for (int j = 0; j < 4; ++j) {
            f32x4 acc = zero4;
            const char* rp = lds + (j * 16 + l15) * 256;
            #pragma unroll
            for (int kb = 0; kb < 4; ++kb) {
                const bf16x8 wf = *(const bf16x8*)(rp + (((kb * 4 + lg) ^ sw7) << 4));
                acc = __builtin_amdgcn_mfma_f32_16x16x32_bf16(wf, a1[kb], acc, 0, 0, 0);
            }
            const float4 fb = *(const float4*)(sm + 256 + j * 16 + lg * 4);
            acc[0] += fb.x; acc[1] += fb.y; acc[2] += fb.z; acc[3] += fb.w;
            h2f[j] = acc;
        }

        // ============ P1: consume F1 (slot1); stage C0 -> slot0 ============
        __syncthreads();
        stage_half(gluv, lds, w, l);

        #pragma unroll
        for (int j = 4; j < 8; ++j) {
            f32x4 acc = zero4;
            const char* rp = lds + HALF_BYTES + ((j - 4) * 16 + l15) * 256;
            #pragma unroll
            for (int kb = 0; kb < 4; ++kb) {
                const bf16x8 wf = *(const bf16x8*)(rp + (((kb * 4 + lg) ^ sw7) << 4));
                acc = __builtin_amdgcn_mfma_f32_16x16x32_bf16(wf, a1[kb], acc, 0, 0, 0);
            }
            const float4 fb = *(const float4*)(sm + 256 + j * 16 + lg * 4);
            acc[0] += fb.x; acc[1] += fb.y; acc[2] += fb.z; acc[3] += fb.w;
            h2f[j] = acc;
        }

        // redistribute h2 D-layout -> B-operand frags (R4/R5-validated)
        bf16x8 b2[4];
        #pragma unroll
        for (int kb2 = 0; kb2 < 4; ++kb2) {
            union U { __bf16 h[4]; int i2[2]; };
            U P, Q;
            P.h[0] = (__bf16)h2f[2 * kb2 + 0][0]; P.h[1] = (__bf16)h2f[2 * kb2 + 0][1];
            P.h[2] = (__bf16)h2f[2 * kb2 + 0][2]; P.h[3] = (__bf16)h2f[2 * kb2 + 0][3];
            Q.h[0] = (__bf16)h2f[2 * kb2 + 1][0]; Q.h[1] = (__bf16)h2f[2 * kb2 + 1][1];
            Q.h[2] = (__bf16)h2f[2 * kb2 + 1][2]; Q.h[3] = (__bf16)h2f[2 * kb2 + 1][3];
            const int px0 = __shfl(P.i2[0], sh0), qx0 = __shfl(Q.i2[0], sh0);
            const int py0 = __shfl(P.i2[1], sh0), qy0 = __shfl(Q.i2[1], sh0);
            const int px1 = __shfl(P.i2[0], sh1), qx1 = __shfl(Q.i2[0], sh1);
            const int py1 = __shfl(P.i2[1], sh1), qy1 = __shfl(Q.i2[1], sh1);
            union V { int ii[4]; bf16x8 vv; } R;
            R.ii[0] = rlo ? px0 : qx0;
            R.ii[1] = rlo ? py0 : qy0;
            R.ii[2] = rlo ? px1 : qx1;
            R.ii[3] = rlo ? py1 : qy1;
            b2[kb2] = R.vv;
        }

        // ============ P2: consume C0 (slot0); stage C1 -> slot1 ============
        __syncthreads();
        stage_half(gluv + 64 * NH, lds + HALF_BYTES, w, l);

        f32x4 fco[8];
        #pragma unroll
        for (int j = 0; j < 4; ++j) {
            f32x4 acc = zero4;
            const char* rp = lds + (j * 16 + l15) * 256;
            #pragma unroll
            for (int kb = 0; kb < 4; ++kb) {
                const bf16x8 wf = *(const bf16x8*)(rp + (((kb * 4 + lg) ^ sw7) << 4));
                acc = __builtin_amdgcn_mfma_f32_16x16x32_bf16(wf, b2[kb], acc, 0, 0, 0);
            }
            const float4 gb = *(const float4*)(sm + 384 + j * 16 + lg * 4);
            acc[0] += gb.x; acc[1] += gb.y; acc[2] += gb.z; acc[3] += gb.w;
            fco[j] = acc;
        }

        // ============ P3: consume C1 (slot1); stage G0 -> slot0 ============
        __syncthreads();
        stage_half(gluv + 128 * NH, lds, w, l);

        #pragma unroll
        for (int j = 4; j < 8; ++j) {
            f32x4 acc = zero4;
            const char* rp = lds + HALF_BYTES + ((j - 4) * 16 + l15) * 256;
            #pragma unroll
            for (int kb = 0; kb < 4; ++kb) {
                const bf16x8 wf = *(const bf16x8*)(rp + (((kb * 4 + lg) ^ sw7) << 4));
                acc = __builtin_amdgcn_mfma_f32_16x16x32_bf16(wf, b2[kb], acc, 0, 0, 0);
            }
            const float4 gb = *(const float4*)(sm + 384 + j * 16 + lg * 4);
            acc[0] += gb.x; acc[1] += gb.y; acc[2] += gb.z; acc[3] += gb.w;
            fco[j] = acc;
        }

        // ============ P4: consume G0 (slot0); stage G1 -> slot1 ============
        __syncthreads();
        stage_half(gluv + 192 * NH, lds + HALF_BYTES, w, l);

        f32x4 sv[8];
        #pragma unroll
        for (int j = 0; j < 4; ++j) {
            f32x4 acc = zero4;
            const char* rp = lds + (j * 16 + l15) * 256;
            #pragma unroll
            for (int kb = 0; kb < 4; ++kb) {
                const bf16x8 wg = *(const bf16x8*)(rp + (((kb * 4 + lg) ^ sw7) << 4));
                acc = __builtin_amdgcn_mfma_f32_16x16x32_bf16(wg, b2[kb], acc, 0, 0, 0);
            }
            const float4 bga = *(const float4*)(sm + 512 + j * 16 + lg * 4);
            const float4 sw4 = *(const float4*)(sm + 640 + j * 16 + lg * 4);
            const float4 sb4 = *(const float4*)(sm + 768 + j * 16 + lg * 4);
            f32x4 s;
            s[0] = fmaf(xv, sw4.x, sb4.x) + fco[j][0] * sigm_f(acc[0] + bga.x);
            s[1] = fmaf(xv, sw4.y, sb4.y) + fco[j][1] * sigm_f(acc[1] + bga.y);
            s[2] = fmaf(xv, sw4.z, sb4.z) + fco[j][2] * sigm_f(acc[2] + bga.z);
            s[3] = fmaf(xv, sw4.w, sb4.w) + fco[j][3] * sigm_f(acc[3] + bga.w);
            sv[j] = s;
        }

        // ====== P5: consume G1 (slot1); stage F0(vn) -> slot0 + smalls(vn) ======
        __syncthreads();
        stage_half(fc2t + (size_t)vn * (NH * NH), lds, w, l);
        stage_smalls(smalls + (size_t)vn * 1024,
                     lds + SMS_OFF + ((i + 1) & 1) * SMS_BYTES, w, l);
        xn = xs[rowoff + vn];
        wn = wts[rowoff + vn];

        #pragma unroll
        for (int j = 4; j < 8; ++j) {
            f32x4 acc = zero4;
            const char* rp = lds + HALF_BYTES + ((j - 4) * 16 + l15) * 256;
            #pragma unroll
            for (int kb = 0; kb < 4; ++kb) {
                const bf16x8 wg = *(const bf16x8*)(rp + (((kb * 4 + lg) ^ sw7) << 4));
                acc = __builtin_amdgcn_mfma_f32_16x16x32_bf16(wg, b2[kb], acc, 0, 0, 0);
            }
            const float4 bga = *(const float4*)(sm + 512 + j * 16 + lg * 4);
            const float4 sw4 = *(const float4*)(sm + 640 + j * 16 + lg * 4);
            const float4 sb4 = *(const float4*)(sm + 768 + j * 16 + lg * 4);
            f32x4 s;
            s[0] = fmaf(xv, sw4.x, sb4.x) + fco[j][0] * sigm_f(acc[0] + bga.x);
            s[1] = fmaf(xv, sw4.y, sb4.y) + fco[j][1] * sigm_f(acc[1] + bga.y);
            s[2] = fmaf(xv, sw4.z, sb4.z) + fco[j][2] * sigm_f(acc[2] + bga.z);
            s[3] = fmaf(xv, sw4.w, sb4.w) + fco[j][3] * sigm_f(acc[3] + bga.w);
            sv[j] = s;
        }

        // ---- LN over 128 features of token l15 (own 32 + 4-lane cross-reduce)
        float t1 = 0.f, t2 = 0.f;
        #pragma unroll
        for (int j = 0; j < 8; ++j) {
            #pragma unroll
            for (int r = 0; r < 4; ++r) { t1 += sv[j][r]; t2 = fmaf(sv[j][r], sv[j][r], t2); }
        }
        t1 += __shfl_xor(t1, 16); t2 += __shfl_xor(t2, 16);
        t1 += __shfl_xor(t1, 32); t2 += __shfl_xor(t2, 32);
        const float mu  = t1 * (1.f / 128.f);
        const float var = t2 * (1.f / 128.f) - mu * mu;
        const float rsv = rsqrtf(fmaxf(var, 0.f) + 1e-5f);

        #pragma unroll
        for (int j = 0; j < 8; ++j) {
            const float4 lg4 = *(const float4*)(lnS + j * 16 + lg * 4);
            const float4 lb4 = *(const float4*)(lnS + 128 + j * 16 + lg * 4);
            const float y0 = fmaf((sv[j][0] - mu) * rsv, lg4.x, lb4.x);
            const float y1 = fmaf((sv[j][1] - mu) * rsv, lg4.y, lb4.y);
            const float y2 = fmaf((sv[j][2] - mu) * rsv, lg4.z, lb4.z);
            const float y3 = fmaf((sv[j][3] - mu) * rsv, lg4.w, lb4.w);
            acc_out[j][0] = fmaf(wv, y0, acc_out[j][0]);
            acc_out[j][1] = fmaf(wv, y1, acc_out[j][1]);
            acc_out[j][2] = fmaf(wv, y2, acc_out[j][2]);
            acc_out[j][3] = fmaf(wv, y3, acc_out[j][3]);
        }

        xv = xn; wv = wn;
    }

    asm volatile("s_waitcnt vmcnt(0)" ::: "memory");   // drain leftover DMA

    // ---- epilogue: atomics (L2-resident per R12: WRITE 65MB total) ----
    #pragma unroll
    for (int j = 0; j < 8; ++j) {
        #pragma unroll
        for (int r = 0; r < 4; ++r)
            atomicAdd(&out[(size_t)(m0 + l15) * NH + j * 16 + lg * 4 + r], acc_out[j][r]);
    }
}

extern "C" void kernel_launch(void* const* d_in, const int* in_sizes, int n_in,
                              void* d_out, int out_size, void* d_ws, size_t ws_size,
                              hipStream_t stream) {
    (void)in_sizes; (void)n_in; (void)out_size; (void)ws_size;

    const float* xs     = (const float*)d_in[0];
    const float* fc1_w  = (const float*)d_in[1];
    const float* fc1_b  = (const float*)d_in[2];
    const float* fc2_w  = (const float*)d_in[3];
    const float* fc2_b  = (const float*)d_in[4];
    const float* glu_w  = (const float*)d_in[5];
    const float* glu_b  = (const float*)d_in[6];
    const float* skip_w = (const float*)d_in[7];
    const float* skip_b = (const float*)d_in[8];
    const float* ln_g   = (const float*)d_in[9];
    const float* ln_b   = (const float*)d_in[10];
    const float* wfc1_w = (const float*)d_in[11];
    const float* wfc1_b = (const float*)d_in[12];
    const float* wfc2_w = (const float*)d_in[13];
    const float* wfc2_b = (const float*)d_in[14];
    const float* wglu_w = (const float*)d_in[15];
    const float* wglu_b = (const float*)d_in[16];
    const float* wln_g  = (const float*)d_in[17];
    const float* wln_b  = (const float*)d_in[18];

    float* out = (float*)d_out;
    float* wts = out + (size_t)NROWS * NH;

    __bf16* fc2t   = (__bf16*)d_ws;
    __bf16* glu16  = fc2t + (size_t)NV * NH * NH;
    float*  smalls = (float*)(glu16 + (size_t)NV * NG * NH);

    hipMemsetAsync(d_out, 0, (size_t)NROWS * NH * sizeof(float), stream);

    k_setup<<<NB_FC2 + NB_GLU + NB_SM + NB_WTS, 256, 0, stream>>>(
        fc2_w, fc2t, glu_w, glu16,
        fc1_w, fc1_b, fc2_b, glu_b, skip_w, skip_b, smalls,
        xs, wfc1_w, wfc1_b, wfc2_w, wfc2_b, wglu_w, wglu_b, wln_g, wln_b, wts);

    k_main<<<(NROWS / 64) * 16, 256, 0, stream>>>(xs, fc2t, glu16, smalls,
                                                  ln_g, ln_b, wts, out);
}

// Round 14
// 337.245 us; speedup vs baseline: 1.0628x; 1.0628x over previous
//
#include <hip/hip_runtime.h>
#include <hip/hip_bf16.h>

#define NROWS 4096
#define NV    204
#define NH    128
#define NG    256

#define SLOT_B     16384
#define SMS_OFF    (3 * SLOT_B)                // 49152
#define SMS_BYTES  3584                        // 896 floats, v-varying smalls
#define LN_OFF     (SMS_OFF + 2 * SMS_BYTES)   // 56320
#define LDS_BYTES  (LN_OFF + 1024)             // 57344 -> 2 blocks/CU

typedef __bf16 bf16x8 __attribute__((ext_vector_type(8)));
typedef float  f32x4  __attribute__((ext_vector_type(4)));

__device__ __forceinline__ float elu_f(float x)  { return x > 0.f ? x : __expf(x) - 1.f; }
__device__ __forceinline__ float sigm_f(float x) { return 1.f / (1.f + __expf(-x)); }

__device__ __forceinline__ void stage16(const void* g, void* l) {
    __builtin_amdgcn_global_load_lds((const __attribute__((address_space(1))) void*)g,
                                     (__attribute__((address_space(3))) void*)l, 16, 0, 0);
}

// 4-wave block stages one 16KB half-tile: wave w moves 4KB (4 x 1KB instrs).
__device__ __forceinline__ void stage_half(const void* src, char* dst, int w, int l) {
    const char* sb = (const char*)src;
    #pragma unroll
    for (int s = 0; s < 4; ++s)
        stage16(sb + (w * 4 + s) * 1024 + l * 16, dst + (w * 4 + s) * 1024);
}

// stage 3584B of smalls: waves 0-2 move 1KB, wave 3 moves 512B (exec-masked).
__device__ __forceinline__ void stage_smalls(const float* src, char* dst, int w, int l) {
    if (w < 3)       stage16((const char*)src + w * 1024 + l * 16, dst + w * 1024);
    else if (l < 32) stage16((const char*)src + 3072 + l * 16,     dst + 3072);
}

// counted-vmcnt phase header (R5-proven skeleton): wait leaves newest DMAs in
// flight, barrier makes completion block-wide; stage is issued AFTER barrier.
#define PSYNC(N) do { \
    asm volatile("s_waitcnt vmcnt(" N ")" ::: "memory"); \
    __builtin_amdgcn_s_barrier(); \
    asm volatile("" ::: "memory"); \
} while (0)

// ============ fused setup ============
#define NB_FC2 NV                 // 204
#define NB_GLU (NV * 16)          // 3264
#define NB_SM  NV                 // 204
#define NB_WTS (NROWS / 8)        // 512

__global__ __launch_bounds__(256) void k_setup(
    const float* __restrict__ fc2_w, __bf16* __restrict__ fc2t,
    const float* __restrict__ glu_w, __bf16* __restrict__ glu16,
    const float* __restrict__ fc1_w, const float* __restrict__ fc1_b,
    const float* __restrict__ fc2_b, const float* __restrict__ glu_b,
    const float* __restrict__ skip_w, const float* __restrict__ skip_b,
    float* __restrict__ smalls,
    const float* __restrict__ xs,
    const float* __restrict__ wfc1_w, const float* __restrict__ wfc1_b,
    const float* __restrict__ wfc2_w, const float* __restrict__ wfc2_b,
    const float* __restrict__ wglu_w, const float* __restrict__ wglu_b,
    const float* __restrict__ wln_g,  const float* __restrict__ wln_b,
    float* __restrict__ wts)
{
    __shared__ float tile[64 * 129];
    __shared__ float sx[8][NV];
    __shared__ float sa[8][NH];
    __shared__ float sg[8][2 * NV];

    const int b = blockIdx.x;
    const int t = threadIdx.x;

    if (b < NB_FC2) {
        // fc2t[v][n][k], row n, 16B-chunk ch stored at ch ^ (n&7)
        const int v = b;
        const float* s = fc2_w + (size_t)v * (NH * NH);
        __bf16*      d = fc2t + (size_t)v * (NH * NH);
        for (int h = 0; h < 2; ++h) {
            __syncthreads();
            for (int i = t; i < 64 * 32; i += 256) {
                const int k = i >> 5, n4 = (i & 31) * 4;
                const float4 f = *(const float4*)(s + (h * 64 + k) * 128 + n4);
                tile[k * 129 + n4 + 0] = f.x;
                tile[k * 129 + n4 + 1] = f.y;
                tile[k * 129 + n4 + 2] = f.z;
                tile[k * 129 + n4 + 3] = f.w;
            }
            __syncthreads();
            for (int i = t; i < 128 * 8; i += 256) {
                const int n = i >> 3, kc = (i & 7) * 8;
                bf16x8 o;
                #pragma unroll
                for (int q = 0; q < 8; ++q) o[q] = (__bf16)tile[(kc + q) * 129 + n];
                const int ch  = h * 8 + (i & 7);
                const int chs = ch ^ (n & 7);
                *(bf16x8*)(d + n * 128 + chs * 8) = o;
            }
        }
        return;
    }

    if (b < NB_FC2 + NB_GLU) {
        // glu16: chunk ch of row g stored at ch ^ (g&7)
        const int idx = (b - NB_FC2) * 256 + t;
        const int ch = idx & 15;
        const int g  = (idx >> 4) & 255;
        const int v  = idx >> 12;
        const float* sp = glu_w + (((size_t)v * NG + g) * NH + ch * 8);
        bf16x8 o;
        #pragma unroll
        for (int q = 0; q < 8; ++q) o[q] = (__bf16)sp[q];
        const int dch = ch ^ (g & 7);
        *(bf16x8*)(glu16 + (((size_t)v * NG + g) * NH) + dch * 8) = o;
        return;
    }

    if (b < NB_FC2 + NB_GLU + NB_SM) {
        // smalls[v] (896 floats, stride 1024): fc1_w@0 fc1_b@128 fc2_b@256
        //   glu_b@384(256) skip_w@640 skip_b@768
        const int v = b - (NB_FC2 + NB_GLU);
        float* dst = smalls + (size_t)v * 1024;
        for (int idx = t; idx < 896; idx += 256) {
            float val;
            if      (idx < 128)  val = fc1_w[v * NH + idx];
            else if (idx < 256)  val = fc1_b[v * NH + idx - 128];
            else if (idx < 384)  val = fc2_b[v * NH + idx - 256];
            else if (idx < 640)  val = glu_b[v * NG + idx - 384];
            else if (idx < 768)  val = skip_w[v * NH + idx - 640];
            else                 val = skip_b[v * NH + idx - 768];
            dst[idx] = val;
        }
        return;
    }

    // ---- wts path ----
    const int r0 = (b - NB_FC2 - NB_GLU - NB_SM) * 8;
    const int tr = t >> 5;
    const int tc = t & 31;

    for (int i = t; i < 8 * NV; i += 256) {
        const int r = i / NV, c = i - r * NV;
        sx[r][c] = xs[(size_t)(r0 + r) * NV + c];
    }
    __syncthreads();

    float acc1[4];
    #pragma unroll
    for (int j = 0; j < 4; ++j) acc1[j] = wfc1_b[tc + 32 * j];
    for (int v = 0; v < NV; ++v) {
        const float xv = sx[tr][v];
        #pragma unroll
        for (int j = 0; j < 4; ++j)
            acc1[j] = fmaf(xv, wfc1_w[v * NH + tc + 32 * j], acc1[j]);
    }
    #pragma unroll
    for (int j = 0; j < 4; ++j) sa[tr][tc + 32 * j] = elu_f(acc1[j]);
    __syncthreads();

    float acc2[4];
    #pragma unroll
    for (int j = 0; j < 4; ++j) acc2[j] = wfc2_b[tc + 32 * j];
    for (int h = 0; h < NH; ++h) {
        const float av = sa[tr][h];
        #pragma unroll
        for (int j = 0; j < 4; ++j)
            acc2[j] = fmaf(av, wfc2_w[h * NH + tc + 32 * j], acc2[j]);
    }
    __syncthreads();
    #pragma unroll
    for (int j = 0; j < 4; ++j) sa[tr][tc + 32 * j] = acc2[j];
    __syncthreads();

    float accg[13];
    #pragma unroll
    for (int gi = 0; gi < 12; ++gi) accg[gi] = wglu_b[tc + 32 * gi];
    accg[12] = (tc < 24) ? wglu_b[tc + 384] : 0.f;
    for (int h = 0; h < NH; ++h) {
        const float av = sa[tr][h];
        #pragma unroll
        for (int gi = 0; gi < 12; ++gi)
            accg[gi] = fmaf(av, wglu_w[h * (2 * NV) + tc + 32 * gi], accg[gi]);
        if (tc < 24) accg[12] = fmaf(av, wglu_w[h * (2 * NV) + tc + 384], accg[12]);
    }
    __syncthreads();
    #pragma unroll
    for (int gi = 0; gi < 12; ++gi) sg[tr][tc + 32 * gi] = accg[gi];
    if (tc < 24) sg[tr][tc + 384] = accg[12];
    __syncthreads();

    float tv[7];
    float s1 = 0.f, s2 = 0.f;
    #pragma unroll
    for (int ii = 0; ii < 7; ++ii) {
        const int c = tc + 32 * ii;
        float val = 0.f;
        if (c < NV) {
            const float hg = sg[tr][c] * sigm_f(sg[tr][c + NV]);
            val = sx[tr][c] + hg;
            s1 += val; s2 = fmaf(val, val, s2);
        }
        tv[ii] = val;
    }
    #pragma unroll
    for (int m = 1; m <= 16; m <<= 1) { s1 += __shfl_xor(s1, m); s2 += __shfl_xor(s2, m); }
    const float mu  = s1 * (1.f / 204.f);
    const float var = s2 * (1.f / 204.f) - mu * mu;
    const float rs  = rsqrtf(fmaxf(var, 0.f) + 1e-5f);

    float mx = -1e30f;
    #pragma unroll
    for (int ii = 0; ii < 7; ++ii) {
        const int c = tc + 32 * ii;
        if (c < NV) {
            const float y = fmaf((tv[ii] - mu) * rs, wln_g[c], wln_b[c]);
            tv[ii] = y;
            mx = fmaxf(mx, y);
        }
    }
    #pragma unroll
    for (int m = 1; m <= 16; m <<= 1) mx = fmaxf(mx, __shfl_xor(mx, m));
    float se = 0.f;
    #pragma unroll
    for (int ii = 0; ii < 7; ++ii) {
        const int c = tc + 32 * ii;
        if (c < NV) {
            const float e = __expf(tv[ii] - mx);
            tv[ii] = e;
            se += e;
        }
    }
    #pragma unroll
    for (int m = 1; m <= 16; m <<= 1) se += __shfl_xor(se, m);
    const float inv = 1.f / se;
    #pragma unroll
    for (int ii = 0; ii < 7; ++ii) {
        const int c = tc + 32 * ii;
        if (c < NV) wts[(size_t)(r0 + tr) * NV + c] = tv[ii] * inv;
    }
}

// ============ main kernel: 3-slot ring, depth-2 prefetch, counted vmcnt ============
// grid = 64 chunks x 8 vg (vg == XCD), block = 256 (4 waves x 16 tokens).
// Phase p consumes slot p%3, stages tile p+2 into slot (p+2)%3 (last read at
// phase p-1; stage issued AFTER the barrier -> R5-proven safe). Counted vmcnt
// (6/6/4/4/4/4, never 0 in-loop) keeps the newest tile's DMA in flight across
// barriers: the drain stall of __syncthreads (R12's 6x vmcnt(0)/iter) is gone.
// KEEP __launch_bounds__(256,2): (256,4) re-creates the R7-R11 spill storm.
__global__ __launch_bounds__(256, 2) void k_main(
    const float*  __restrict__ xs,
    const __bf16* __restrict__ fc2t,    // [v][n][k], chunk^=(n&7) swizzled
    const __bf16* __restrict__ glu16,   // [v][g][k], chunk^=(g&7) swizzled
    const float*  __restrict__ smalls,  // [v][1024f], 896 used
    const float*  __restrict__ ln_g,
    const float*  __restrict__ ln_b,
    const float*  __restrict__ wts,
    float*        __restrict__ out)
{
    __shared__ __align__(16) char lds[LDS_BYTES];

    const int tid = threadIdx.x;
    const int w   = tid >> 6;
    const int l   = tid & 63;
    const int l15 = l & 15;
    const int lg  = l >> 4;
    const int sw7 = l15 & 7;

    const int vg = blockIdx.x & 7;                    // == XCD
    const int m0 = (blockIdx.x >> 3) * 64 + w * 16;   // wave's 16 tokens
    const int nv = (NV - 1 - vg) / 8 + 1;
    const size_t rowoff = (size_t)(m0 + l15) * NV;

    char* const slot0 = lds;
    char* const slot1 = lds + SLOT_B;
    char* const slot2 = lds + 2 * SLOT_B;

    const f32x4 zero4 = {0.f, 0.f, 0.f, 0.f};
    f32x4 acc_out[8];
    #pragma unroll
    for (int j = 0; j < 8; ++j) acc_out[j] = zero4;

    const int  sh0 = l15 + ((lg & 1) << 5);   // redistribute shfl sources (R4-validated)
    const int  sh1 = sh0 + 16;
    const bool rlo = (lg < 2);

    const float* lnS = (const float*)(lds + LN_OFF);

    // ---- prologue (issue order matters for the counted waits):
    //   ln(oldest) -> F0 -> smalls -> F1 -> x -> w   (mimics steady P4/P5 tail)
    float xv, wv, xn, wn;
    {
        if (w == 0) {
            const char* p = (l < 32) ? ((const char*)ln_g + l * 16)
                                     : ((const char*)ln_b + (l - 32) * 16);
            stage16(p, lds + LN_OFF);
        }
        stage_half(fc2t + (size_t)vg * (NH * NH), slot0, w, l);            // F0
        stage_smalls(smalls + (size_t)vg * 1024, lds + SMS_OFF, w, l);     // smalls(0)
        stage_half(fc2t + (size_t)vg * (NH * NH) + 64 * NH, slot1, w, l);  // F1
        xv = xs[rowoff + vg];
        wv = wts[rowoff + vg];
    }

    for (int i = 0; i < nv; ++i) {
        const int v  = vg + 8 * i;
        const int vn = (i + 1 < nv) ? v + 8 : v;    // clamped (uniform counts)
        const float* sm = (const float*)(lds + SMS_OFF + (i & 1) * SMS_BYTES);
        const __bf16* gluv = glu16 + (size_t)v * (NG * NH);

        // ====== P0: consume F0 @slot0; stage C0 -> slot2 ======
        PSYNC("6");                                    // drains F0+smalls; F1,x,w in flight
        stage_half(gluv, slot2, w, l);

        bf16x8 a1[4];
        #pragma unroll
        for (int kb = 0; kb < 4; ++kb) {
            const int k0 = kb * 32 + lg * 8;
            const float4 w0 = *(const float4*)(sm + k0);
            const float4 w1 = *(const float4*)(sm + k0 + 4);
            const float4 b0 = *(const float4*)(sm + 128 + k0);
            const float4 b1 = *(const float4*)(sm + 128 + k0 + 4);
            bf16x8 af;
            af[0] = (__bf16)elu_f(fmaf(xv, w0.x, b0.x));
            af[1] = (__bf16)elu_f(fmaf(xv, w0.y, b0.y));
            af[2] = (__bf16)elu_f(fmaf(xv, w0.z, b0.z));
            af[3] = (__bf16)elu_f(fmaf(xv, w0.w, b0.w));
            af[4] = (__bf16)elu_f(fmaf(xv, w1.x, b1.x));
            af[5] = (__bf16)elu_f(fmaf(xv, w1.y, b1.y));
            af[6] = (__bf16)elu_f(fmaf(xv, w1.z, b1.z));
            af[7] = (__bf16)elu_f(fmaf(xv, w1.w, b1.w));
            a1[kb] = af;
        }

        f32x4 h2f[8];
        #pragma unroll
        for (int j = 0; j < 4; ++j) {
            f32x4 acc = zero4;
            const char* rp = slot0 + (j * 16 + l15) * 256;
            #pragma unroll
            for (int kb = 0; kb < 4; ++kb) {
                const bf16x8 wf = *(const bf16x8*)(rp + (((kb * 4 + lg) ^ sw7) << 4));
                acc = __builtin_amdgcn_mfma_f32_16x16x32_bf16(wf, a1[kb], acc, 0, 0, 0);
            }
            const float4 fb = *(const float4*)(sm + 256 + j * 16 + lg * 4);
            acc[0] += fb.x; acc[1] += fb.y; acc[2] += fb.z; acc[3] += fb.w;
            h2f[j] = acc;
        }

        // ====== P1: consume F1 @slot1; stage C1 -> slot0 ======
        PSYNC("6");                                    // drains F1; C0,x,w in flight
        stage_half(gluv + 64 * NH, slot0, w, l);

        #pragma unroll
        for (int j = 4; j < 8; ++j) {
            f32x4 acc = zero4;
            const char* rp = slot1 + ((j - 4) * 16 + l15) * 256;
            #pragma unroll
            for (int kb = 0; kb < 4; ++kb) {
                const bf16x8 wf = *(const bf16x8*)(rp + (((kb * 4 + lg) ^ sw7) << 4));
                acc = __builtin_amdgcn_mfma_f32_16x16x32_bf16(wf, a1[kb], acc, 0, 0, 0);
            }
            const float4 fb = *(const float4*)(sm + 256 + j * 16 + lg * 4);
            acc[0] += fb.x; acc[1] += fb.y; acc[2] += fb.z; acc[3] += fb.w;
            h2f[j] = acc;
        }

        // redistribute h2 D-layout -> B-operand frags (R4/R5-validated)
        bf16x8 b2[4];
        #pragma unroll
        for (int kb2 = 0; kb2 < 4; ++kb2) {
            union U { __bf16 h[4]; int i2[2]; };
            U P, Q;
            P.h[0] = (__bf16)h2f[2 * kb2 + 0][0]; P.h[1] = (__bf16)h2f[2 * kb2 + 0][1];
            P.h[2] = (__bf16)h2f[2 * kb2 + 0][2]; P.h[3] = (__bf16)h2f[2 * kb2 + 0][3];
            Q.h[0] = (__bf16)h2f[2 * kb2 + 1][0]; Q.h[1] = (__bf16)h2f[2 * kb2 + 1][1];
            Q.h[2] = (__bf16)h2f[2 * kb2 + 1][2]; Q.h[3] = (__bf16)h2f[2 * kb2 + 1][3];
            const int px0 = __shfl(P.i2[0], sh0), qx0 = __shfl(Q.i2[0], sh0);
            const int py0 = __shfl(P.i2[1], sh0), qy0 = __shfl(Q.i2[1], sh0);
            const int px1 = __shfl(P.i2[0], sh1), qx1 = __shfl(Q.i2[0], sh1);
            const int py1 = __shfl(P.i2[1], sh1), qy1 = __shfl(Q.i2[1], sh1);
            union V { int ii[4]; bf16x8 vv; } R;
            R.ii[0] = rlo ? px0 : qx0;
            R.ii[1] = rlo ? py0 : qy0;
            R.ii[2] = rlo ? px1 : qx1;
            R.ii[3] = rlo ? py1 : qy1;
            b2[kb2] = R.vv;
        }

        // ====== P2: consume C0 @slot2; stage G0 -> slot1 ======
        PSYNC("4");                                    // drains C0; C1 in flight
        stage_half(gluv + 128 * NH, slot1, w, l);

        f32x4 fco[8];
        #pragma unroll
        for (int j = 0; j < 4; ++j) {
            f32x4 acc = zero4;
            const char* rp = slot2 + (j * 16 + l15) * 256;
            #pragma unroll
            for (int kb = 0; kb < 4; ++kb) {
                const bf16x8 wf = *(const bf16x8*)(rp + (((kb * 4 + lg) ^ sw7) << 4));
                acc = __builtin_amdgcn_mfma_f32_16x16x32_bf16(wf, b2[kb], acc, 0, 0, 0);
            }
            const float4 gb = *(const float4*)(sm + 384 + j * 16 + lg * 4);
            acc[0] += gb.x; acc[1] += gb.y; acc[2] += gb.z; acc[3] += gb.w;
            fco[j] = acc;
        }

        // ====== P3: consume C1 @slot0; stage G1 -> slot2 ======
        PSYNC("4");
        stage_half(gluv + 192 * NH, slot2, w, l);

        #pragma unroll
        for (int j = 4; j < 8; ++j) {
            f32x4 acc = zero4;
            const char* rp = slot0 + ((j - 4) * 16 + l15) * 256;
            #pragma unroll
            for (int kb = 0; kb < 4; ++kb) {
                const bf16x8 wf = *(const bf16x8*)(rp + (((kb * 4 + lg) ^ sw7) << 4));
                acc = __builtin_amdgcn_mfma_f32_16x16x32_bf16(wf, b2[kb], acc, 0, 0, 0);
            }
            const float4 gb = *(const float4*)(sm + 384 + j * 16 + lg * 4);
            acc[0] += gb.x; acc[1] += gb.y; acc[2] += gb.z; acc[3] += gb.w;
            fco[j] = acc;
        }

        // ====== P4: consume G0 @slot1; stage F0(vn) -> slot0 ======
        PSYNC("4");
        stage_half(fc2t + (size_t)vn * (NH * NH), slot0, w, l);

        f32x4 sv[8];
        #pragma unroll
        for (int j = 0; j < 4; ++j) {
            f32x4 acc = zero4;
            const char* rp = slot1 + (j * 16 + l15) * 256;
            #pragma unroll
            for (int kb = 0; kb < 4; ++kb) {
                const bf16x8 wg = *(const bf16x8*)(rp + (((kb * 4 + lg) ^ sw7) << 4));
                acc = __builtin_amdgcn_mfma_f32_16x16x32_bf16(wg, b2[kb], acc, 0, 0, 0);
            }
            const float4 bga = *(const float4*)(sm + 512 + j * 16 + lg * 4);
            const float4 sw4 = *(const float4*)(sm + 640 + j * 16 + lg * 4);
            const float4 sb4 = *(const float4*)(sm + 768 + j * 16 + lg * 4);
            f32x4 s;
            s[0] = fmaf(xv, sw4.x, sb4.x) + fco[j][0] * sigm_f(acc[0] + bga.x);
            s[1] = fmaf(xv, sw4.y, sb4.y) + fco[j][1] * sigm_f(acc[1] + bga.y);
            s[2] = fmaf(xv, sw4.z, sb4.z) + fco[j][2] * sigm_f(acc[2] + bga.z);
            s[3] = fmaf(xv, sw4.w, sb4.w) + fco[j][3] * sigm_f(acc[3] + bga.w);
            sv[j] = s;
        }

        // ====== P5: consume G1 @slot2; stage smalls(vn) + F1(vn)->slot1 + x/w ======
        PSYNC("4");
        stage_smalls(smalls + (size_t)vn * 1024,
                     lds + SMS_OFF + ((i + 1) & 1) * SMS_BYTES, w, l);     // oldest of P5
        stage_half(fc2t + (size_t)vn * (NH * NH) + 64 * NH, slot1, w, l);  // F1'
        xn = xs[rowoff + vn];
        wn = wts[rowoff + vn];

        #pragma unroll
        for (int j = 4; j < 8; ++j) {
            f32x4 acc = zero4;
            const char* rp = slot2 + ((j - 4) * 16 + l15) * 256;
            #pragma unroll
            for (int kb = 0; kb < 4; ++kb) {
                const bf16x8 wg = *(const bf16x8*)(rp + (((kb * 4 + lg) ^ sw7) << 4));
                acc = __builtin_amdgcn_mfma_f32_16x16x32_bf16(wg, b2[kb], acc, 0, 0, 0);
            }
            const float4 bga = *(const float4*)(sm + 512 + j * 16 + lg * 4);
            const float4 sw4 = *(const float4*)(sm + 640 + j * 16 + lg * 4);
            const float4 sb4 = *(const float4*)(sm + 768 + j * 16 + lg * 4);
            f32x4 s;
            s[0] = fmaf(xv, sw4.x, sb4.x) + fco[j][0] * sigm_f(acc[0] + bga.x);
            s[1] = fmaf(xv, sw4.y, sb4.y) + fco[j][1] * sigm_f(acc[1] + bga.y);
            s[2] = fmaf(xv, sw4.z, sb4.z) + fco[j][2] * sigm_f(acc[2] + bga.z);
            s[3] = fmaf(xv, sw4.w, sb4.w) + fco[j][3] * sigm_f(acc[3] + bga.w);
            sv[j] = s;
        }

        // ---- LN over 128 features of token l15 (own 32 + 4-lane cross-reduce)
        float t1 = 0.f, t2 = 0.f;
        #pragma unroll
        for (int j = 0; j < 8; ++j) {
            #pragma unroll
            for (int r = 0; r < 4; ++r) { t1 += sv[j][r]; t2 = fmaf(sv[j][r], sv[j][r], t2); }
        }
        t1 += __shfl_xor(t1, 16); t2 += __shfl_xor(t2, 16);
        t1 += __shfl_xor(t1, 32); t2 += __shfl_xor(t2, 32);
        const float mu  = t1 * (1.f / 128.f);
        const float var = t2 * (1.f / 128.f) - mu * mu;
        const float rsv = rsqrtf(fmaxf(var, 0.f) + 1e-5f);

        #pragma unroll
        for (int j = 0; j < 8; ++j) {
            const float4 lg4 = *(const float4*)(lnS + j * 16 + lg * 4);
            const float4 lb4 = *(const float4*)(lnS + 128 + j * 16 + lg * 4);
            const float y0 = fmaf((sv[j][0] - mu) * rsv, lg4.x, lb4.x);
            const float y1 = fmaf((sv[j][1] - mu) * rsv, lg4.y, lb4.y);
            const float y2 = fmaf((sv[j][2] - mu) * rsv, lg4.z, lb4.z);
            const float y3 = fmaf((sv[j][3] - mu) * rsv, lg4.w, lb4.w);
            acc_out[j][0] = fmaf(wv, y0, acc_out[j][0]);
            acc_out[j][1] = fmaf(wv, y1, acc_out[j][1]);
            acc_out[j][2] = fmaf(wv, y2, acc_out[j][2]);
            acc_out[j][3] = fmaf(wv, y3, acc_out[j][3]);
        }

        xv = xn; wv = wn;
    }

    asm volatile("s_waitcnt vmcnt(0)" ::: "memory");   // drain leftover DMA

    // ---- epilogue: atomics; 8 sharers per line, one per XCD (R12-proven) ----
    #pragma unroll
    for (int j = 0; j < 8; ++j) {
        #pragma unroll
        for (int r = 0; r < 4; ++r)
            atomicAdd(&out[(size_t)(m0 + l15) * NH + j * 16 + lg * 4 + r], acc_out[j][r]);
    }
}

extern "C" void kernel_launch(void* const* d_in, const int* in_sizes, int n_in,
                              void* d_out, int out_size, void* d_ws, size_t ws_size,
                              hipStream_t stream) {
    (void)in_sizes; (void)n_in; (void)out_size; (void)ws_size;

    const float* xs     = (const float*)d_in[0];
    const float* fc1_w  = (const float*)d_in[1];
    const float* fc1_b  = (const float*)d_in[2];
    const float* fc2_w  = (const float*)d_in[3];
    const float* fc2_b  = (const float*)d_in[4];
    const float* glu_w  = (const float*)d_in[5];
    const float* glu_b  = (const float*)d_in[6];
    const float* skip_w = (const float*)d_in[7];
    const float* skip_b = (const float*)d_in[8];
    const float* ln_g   = (const float*)d_in[9];
    const float* ln_b   = (const float*)d_in[10];
    const float* wfc1_w = (const float*)d_in[11];
    const float* wfc1_b = (const float*)d_in[12];
    const float* wfc2_w = (const float*)d_in[13];
    const float* wfc2_b = (const float*)d_in[14];
    const float* wglu_w = (const float*)d_in[15];
    const float* wglu_b = (const float*)d_in[16];
    const float* wln_g  = (const float*)d_in[17];
    const float* wln_b  = (const float*)d_in[18];

    float* out = (float*)d_out;
    float* wts = out + (size_t)NROWS * NH;

    __bf16* fc2t   = (__bf16*)d_ws;
    __bf16* glu16  = fc2t + (size_t)NV * NH * NH;
    float*  smalls = (float*)(glu16 + (size_t)NV * NG * NH);

    hipMemsetAsync(d_out, 0, (size_t)NROWS * NH * sizeof(float), stream);

    k_setup<<<NB_FC2 + NB_GLU + NB_SM + NB_WTS, 256, 0, stream>>>(
        fc2_w, fc2t, glu_w, glu16,
        fc1_w, fc1_b, fc2_b, glu_b, skip_w, skip_b, smalls,
        xs, wfc1_w, wfc1_b, wfc2_w, wfc2_b, wglu_w, wglu_b, wln_g, wln_b, wts);

    k_main<<<(NROWS / 64) * 8, 256, 0, stream>>>(xs, fc2t, glu16, smalls,
                                                 ln_g, ln_b, wts, out);
}

// Round 17
// 330.740 us; speedup vs baseline: 1.0837x; 1.0197x over previous
//
#include <hip/hip_runtime.h>
#include <hip/hip_bf16.h>

#define NROWS 4096
#define NV    204
#define NH    128
#define NG    256

#define SLOT_B     16384
#define SMS_OFF    (3 * SLOT_B)                // 49152
#define SMS_BYTES  3584                        // 896 floats, v-varying smalls
#define LN_OFF     (SMS_OFF + 2 * SMS_BYTES)   // 56320
#define LDS_BYTES  (LN_OFF + 1024)             // 57344 -> 2 blocks/CU

typedef __bf16 bf16x8 __attribute__((ext_vector_type(8)));
typedef float  f32x4  __attribute__((ext_vector_type(4)));

__device__ __forceinline__ float elu_f(float x)  { return x > 0.f ? x : __expf(x) - 1.f; }
__device__ __forceinline__ float sigm_f(float x) { return 1.f / (1.f + __expf(-x)); }

__device__ __forceinline__ void stage16(const void* g, void* l) {
    __builtin_amdgcn_global_load_lds((const __attribute__((address_space(1))) void*)g,
                                     (__attribute__((address_space(3))) void*)l, 16, 0, 0);
}

// 4-wave block stages one 16KB half-tile: wave w moves 4KB (4 x 1KB instrs).
__device__ __forceinline__ void stage_half(const void* src, char* dst, int w, int l) {
    const char* sb = (const char*)src;
    #pragma unroll
    for (int s = 0; s < 4; ++s)
        stage16(sb + (w * 4 + s) * 1024 + l * 16, dst + (w * 4 + s) * 1024);
}

// stage 3584B of smalls: waves 0-2 move 1KB, wave 3 moves 512B (exec-masked).
__device__ __forceinline__ void stage_smalls(const float* src, char* dst, int w, int l) {
    if (w < 3)       stage16((const char*)src + w * 1024 + l * 16, dst + w * 1024);
    else if (l < 32) stage16((const char*)src + 3072 + l * 16,     dst + 3072);
}

// counted-vmcnt phase header (R5/R14-proven): wait leaves newest DMAs in
// flight, barrier makes completion block-wide; stage issued AFTER barrier.
#define PSYNC(N) do { \
    asm volatile("s_waitcnt vmcnt(" N ")" ::: "memory"); \
    __builtin_amdgcn_s_barrier(); \
    asm volatile("" ::: "memory"); \
} while (0)

// ============ fused setup ============
#define NB_FC2 NV                 // 204
#define NB_GLU (NV * 16)          // 3264
#define NB_SM  NV                 // 204
#define NB_WTS (NROWS / 8)        // 512

__global__ __launch_bounds__(256) void k_setup(
    const float* __restrict__ fc2_w, __bf16* __restrict__ fc2t,
    const float* __restrict__ glu_w, __bf16* __restrict__ glu16,
    const float* __restrict__ fc1_w, const float* __restrict__ fc1_b,
    const float* __restrict__ fc2_b, const float* __restrict__ glu_b,
    const float* __restrict__ skip_w, const float* __restrict__ skip_b,
    float* __restrict__ smalls,
    const float* __restrict__ xs,
    const float* __restrict__ wfc1_w, const float* __restrict__ wfc1_b,
    const float* __restrict__ wfc2_w, const float* __restrict__ wfc2_b,
    const float* __restrict__ wglu_w, const float* __restrict__ wglu_b,
    const float* __restrict__ wln_g,  const float* __restrict__ wln_b,
    float* __restrict__ wts)
{
    __shared__ float tile[64 * 129];
    __shared__ float sx[8][NV];
    __shared__ float sa[8][NH];
    __shared__ float sg[8][2 * NV];

    const int b = blockIdx.x;
    const int t = threadIdx.x;

    if (b < NB_FC2) {
        // fc2t[v][n][k], row n, 16B-chunk ch stored at ch ^ (n&15)  [R17: 4-bit]
        const int v = b;
        const float* s = fc2_w + (size_t)v * (NH * NH);
        __bf16*      d = fc2t + (size_t)v * (NH * NH);
        for (int h = 0; h < 2; ++h) {
            __syncthreads();
            for (int i = t; i < 64 * 32; i += 256) {
                const int k = i >> 5, n4 = (i & 31) * 4;
                const float4 f = *(const float4*)(s + (h * 64 + k) * 128 + n4);
                tile[k * 129 + n4 + 0] = f.x;
                tile[k * 129 + n4 + 1] = f.y;
                tile[k * 129 + n4 + 2] = f.z;
                tile[k * 129 + n4 + 3] = f.w;
            }
            __syncthreads();
            for (int i = t; i < 128 * 8; i += 256) {
                const int n = i >> 3, kc = (i & 7) * 8;
                bf16x8 o;
                #pragma unroll
                for (int q = 0; q < 8; ++q) o[q] = (__bf16)tile[(kc + q) * 129 + n];
                const int ch  = h * 8 + (i & 7);
                const int chs = ch ^ (n & 15);
                *(bf16x8*)(d + n * 128 + chs * 8) = o;
            }
        }
        return;
    }

    if (b < NB_FC2 + NB_GLU) {
        // glu16: chunk ch of row g stored at ch ^ (g&15)  [R17: 4-bit]
        const int idx = (b - NB_FC2) * 256 + t;
        const int ch = idx & 15;
        const int g  = (idx >> 4) & 255;
        const int v  = idx >> 12;
        const float* sp = glu_w + (((size_t)v * NG + g) * NH + ch * 8);
        bf16x8 o;
        #pragma unroll
        for (int q = 0; q < 8; ++q) o[q] = (__bf16)sp[q];
        const int dch = ch ^ (g & 15);
        *(bf16x8*)(glu16 + (((size_t)v * NG + g) * NH) + dch * 8) = o;
        return;
    }

    if (b < NB_FC2 + NB_GLU + NB_SM) {
        // smalls[v] (896 floats, stride 1024): fc1_w@0 fc1_b@128 fc2_b@256
        //   glu_b@384(256) skip_w@640 skip_b@768
        const int v = b - (NB_FC2 + NB_GLU);
        float* dst = smalls + (size_t)v * 1024;
        for (int idx = t; idx < 896; idx += 256) {
            float val;
            if      (idx < 128)  val = fc1_w[v * NH + idx];
            else if (idx < 256)  val = fc1_b[v * NH + idx - 128];
            else if (idx < 384)  val = fc2_b[v * NH + idx - 256];
            else if (idx < 640)  val = glu_b[v * NG + idx - 384];
            else if (idx < 768)  val = skip_w[v * NH + idx - 640];
            else                 val = skip_b[v * NH + idx - 768];
            dst[idx] = val;
        }
        return;
    }

    // ---- wts path ----
    const int r0 = (b - NB_FC2 - NB_GLU - NB_SM) * 8;
    const int tr = t >> 5;
    const int tc = t & 31;

    for (int i = t; i < 8 * NV; i += 256) {
        const int r = i / NV, c = i - r * NV;
        sx[r][c] = xs[(size_t)(r0 + r) * NV + c];
    }
    __syncthreads();

    float acc1[4];
    #pragma unroll
    for (int j = 0; j < 4; ++j) acc1[j] = wfc1_b[tc + 32 * j];
    for (int v = 0; v < NV; ++v) {
        const float xv = sx[tr][v];
        #pragma unroll
        for (int j = 0; j < 4; ++j)
            acc1[j] = fmaf(xv, wfc1_w[v * NH + tc + 32 * j], acc1[j]);
    }
    #pragma unroll
    for (int j = 0; j < 4; ++j) sa[tr][tc + 32 * j] = elu_f(acc1[j]);
    __syncthreads();

    float acc2[4];
    #pragma unroll
    for (int j = 0; j < 4; ++j) acc2[j] = wfc2_b[tc + 32 * j];
    for (int h = 0; h < NH; ++h) {
        const float av = sa[tr][h];
        #pragma unroll
        for (int j = 0; j < 4; ++j)
            acc2[j] = fmaf(av, wfc2_w[h * NH + tc + 32 * j], acc2[j]);
    }
    __syncthreads();
    #pragma unroll
    for (int j = 0; j < 4; ++j) sa[tr][tc + 32 * j] = acc2[j];
    __syncthreads();

    float accg[13];
    #pragma unroll
    for (int gi = 0; gi < 12; ++gi) accg[gi] = wglu_b[tc + 32 * gi];
    accg[12] = (tc < 24) ? wglu_b[tc + 384] : 0.f;
    for (int h = 0; h < NH; ++h) {
        const float av = sa[tr][h];
        #pragma unroll
        for (int gi = 0; gi < 12; ++gi)
            accg[gi] = fmaf(av, wglu_w[h * (2 * NV) + tc + 32 * gi], accg[gi]);
        if (tc < 24) accg[12] = fmaf(av, wglu_w[h * (2 * NV) + tc + 384], accg[12]);
    }
    __syncthreads();
    #pragma unroll
    for (int gi = 0; gi < 12; ++gi) sg[tr][tc + 32 * gi] = accg[gi];
    if (tc < 24) sg[tr][tc + 384] = accg[12];
    __syncthreads();

    float tv[7];
    float s1 = 0.f, s2 = 0.f;
    #pragma unroll
    for (int ii = 0; ii < 7; ++ii) {
        const int c = tc + 32 * ii;
        float val = 0.f;
        if (c < NV) {
            const float hg = sg[tr][c] * sigm_f(sg[tr][c + NV]);
            val = sx[tr][c] + hg;
            s1 += val; s2 = fmaf(val, val, s2);
        }
        tv[ii] = val;
    }
    #pragma unroll
    for (int m = 1; m <= 16; m <<= 1) { s1 += __shfl_xor(s1, m); s2 += __shfl_xor(s2, m); }
    const float mu  = s1 * (1.f / 204.f);
    const float var = s2 * (1.f / 204.f) - mu * mu;
    const float rs  = rsqrtf(fmaxf(var, 0.f) + 1e-5f);

    float mx = -1e30f;
    #pragma unroll
    for (int ii = 0; ii < 7; ++ii) {
        const int c = tc + 32 * ii;
        if (c < NV) {
            const float y = fmaf((tv[ii] - mu) * rs, wln_g[c], wln_b[c]);
            tv[ii] = y;
            mx = fmaxf(mx, y);
        }
    }
    #pragma unroll
    for (int m = 1; m <= 16; m <<= 1) mx = fmaxf(mx, __shfl_xor(mx, m));
    float se = 0.f;
    #pragma unroll
    for (int ii = 0; ii < 7; ++ii) {
        const int c = tc + 32 * ii;
        if (c < NV) {
            const float e = __expf(tv[ii] - mx);
            tv[ii] = e;
            se += e;
        }
    }
    #pragma unroll
    for (int m = 1; m <= 16; m <<= 1) se += __shfl_xor(se, m);
    const float inv = 1.f / se;
    #pragma unroll
    for (int ii = 0; ii < 7; ++ii) {
        const int c = tc + 32 * ii;
        if (c < NV) wts[(size_t)(r0 + tr) * NV + c] = tv[ii] * inv;
    }
}

// ============ main kernel: R14 structure + full 4-bit chunk XOR ============
// grid = 64 chunks x 8 vg (vg == XCD), block = 256 (4 waves x 16 tokens).
// 3-slot ring, depth-2 prefetch, counted vmcnt 6/6/4/4/4/4 (R14, passed).
// ONLY change vs R14: swizzle ^(row&7) -> ^(row&15). The 3-bit XOR left
// lanes l15 and l15+8 colliding on every ds_read_b128 (2.34e7 conflict
// cycles); 4-bit is bijective over all 16 chunk slots.
// KEEP __launch_bounds__(256,2): (256,4) re-creates the R7-R11 spill storm.
__global__ __launch_bounds__(256, 2) void k_main(
    const float*  __restrict__ xs,
    const __bf16* __restrict__ fc2t,    // [v][n][k], chunk^=(n&15) swizzled
    const __bf16* __restrict__ glu16,   // [v][g][k], chunk^=(g&15) swizzled
    const float*  __restrict__ smalls,  // [v][1024f], 896 used
    const float*  __restrict__ ln_g,
    const float*  __restrict__ ln_b,
    const float*  __restrict__ wts,
    float*        __restrict__ out)
{
    __shared__ __align__(16) char lds[LDS_BYTES];

    const int tid = threadIdx.x;
    const int w   = tid >> 6;
    const int l   = tid & 63;
    const int l15 = l & 15;
    const int lg  = l >> 4;

    const int vg = blockIdx.x & 7;                    // == XCD
    const int m0 = (blockIdx.x >> 3) * 64 + w * 16;   // wave's 16 tokens
    const int nv = (NV - 1 - vg) / 8 + 1;
    const size_t rowoff = (size_t)(m0 + l15) * NV;

    char* const slot0 = lds;
    char* const slot1 = lds + SLOT_B;
    char* const slot2 = lds + 2 * SLOT_B;

    const f32x4 zero4 = {0.f, 0.f, 0.f, 0.f};
    f32x4 acc_out[8];
    #pragma unroll
    for (int j = 0; j < 8; ++j) acc_out[j] = zero4;

    const int  sh0 = l15 + ((lg & 1) << 5);   // redistribute shfl sources (R4-validated)
    const int  sh1 = sh0 + 16;
    const bool rlo = (lg < 2);

    const float* lnS = (const float*)(lds + LN_OFF);

    // ---- prologue (issue order matters for the counted waits):
    //   ln(oldest) -> F0 -> smalls -> F1 -> x -> w   (mimics steady P4/P5 tail)
    float xv, wv, xn, wn;
    {
        if (w == 0) {
            const char* p = (l < 32) ? ((const char*)ln_g + l * 16)
                                     : ((const char*)ln_b + (l - 32) * 16);
            stage16(p, lds + LN_OFF);
        }
        stage_half(fc2t + (size_t)vg * (NH * NH), slot0, w, l);            // F0
        stage_smalls(smalls + (size_t)vg * 1024, lds + SMS_OFF, w, l);     // smalls(0)
        stage_half(fc2t + (size_t)vg * (NH * NH) + 64 * NH, slot1, w, l);  // F1
        xv = xs[rowoff + vg];
        wv = wts[rowoff + vg];
    }

    for (int i = 0; i < nv; ++i) {
        const int v  = vg + 8 * i;
        const int vn = (i + 1 < nv) ? v + 8 : v;    // clamped (uniform counts)
        const float* sm = (const float*)(lds + SMS_OFF + (i & 1) * SMS_BYTES);
        const __bf16* gluv = glu16 + (size_t)v * (NG * NH);

        // ====== P0: consume F0 @slot0; stage C0 -> slot2 ======
        PSYNC("6");                                    // drains F0+smalls; F1,x,w in flight
        stage_half(gluv, slot2, w, l);

        bf16x8 a1[4];
        #pragma unroll
        for (int kb = 0; kb < 4; ++kb) {
            const int k0 = kb * 32 + lg * 8;
            const float4 w0 = *(const float4*)(sm + k0);
            const float4 w1 = *(const float4*)(sm + k0 + 4);
            const float4 b0 = *(const float4*)(sm + 128 + k0);
            const float4 b1 = *(const float4*)(sm + 128 + k0 + 4);
            bf16x8 af;
            af[0] = (__bf16)elu_f(fmaf(xv, w0.x, b0.x));
            af[1] = (__bf16)elu_f(fmaf(xv, w0.y, b0.y));
            af[2] = (__bf16)elu_f(fmaf(xv, w0.z, b0.z));
            af[3] = (__bf16)elu_f(fmaf(xv, w0.w, b0.w));
            af[4] = (__bf16)elu_f(fmaf(xv, w1.x, b1.x));
            af[5] = (__bf16)elu_f(fmaf(xv, w1.y, b1.y));
            af[6] = (__bf16)elu_f(fmaf(xv, w1.z, b1.z));
            af[7] = (__bf16)elu_f(fmaf(xv, w1.w, b1.w));
            a1[kb] = af;
        }

        f32x4 h2f[8];
        #pragma unroll
        for (int j = 0; j < 4; ++j) {
            f32x4 acc = zero4;
            const char* rp = slot0 + (j * 16 + l15) * 256;
            #pragma unroll
            for (int kb = 0; kb < 4; ++kb) {
                const bf16x8 wf = *(const bf16x8*)(rp + (((kb * 4 + lg) ^ l15) << 4));
                acc = __builtin_amdgcn_mfma_f32_16x16x32_bf16(wf, a1[kb], acc, 0, 0, 0);
            }
            const float4 fb = *(const float4*)(sm + 256 + j * 16 + lg * 4);
            acc[0] += fb.x; acc[1] += fb.y; acc[2] += fb.z; acc[3] += fb.w;
            h2f[j] = acc;
        }

        // ====== P1: consume F1 @slot1; stage C1 -> slot0 ======
        PSYNC("6");                                    // drains F1; C0,x,w in flight
        stage_half(gluv + 64 * NH, slot0, w, l);

        #pragma unroll
        for (int j = 4; j < 8; ++j) {
            f32x4 acc = zero4;
            const char* rp = slot1 + ((j - 4) * 16 + l15) * 256;
            #pragma unroll
            for (int kb = 0; kb < 4; ++kb) {
                const bf16x8 wf = *(const bf16x8*)(rp + (((kb * 4 + lg) ^ l15) << 4));
                acc = __builtin_amdgcn_mfma_f32_16x16x32_bf16(wf, a1[kb], acc, 0, 0, 0);
            }
            const float4 fb = *(const float4*)(sm + 256 + j * 16 + lg * 4);
            acc[0] += fb.x; acc[1] += fb.y; acc[2] += fb.z; acc[3] += fb.w;
            h2f[j] = acc;
        }

        // redistribute h2 D-layout -> B-operand frags (R4/R5-validated)
        bf16x8 b2[4];
        #pragma unroll
        for (int kb2 = 0; kb2 < 4; ++kb2) {
            union U { __bf16 h[4]; int i2[2]; };
            U P, Q;
            P.h[0] = (__bf16)h2f[2 * kb2 + 0][0]; P.h[1] = (__bf16)h2f[2 * kb2 + 0][1];
            P.h[2] = (__bf16)h2f[2 * kb2 + 0][2]; P.h[3] = (__bf16)h2f[2 * kb2 + 0][3];
            Q.h[0] = (__bf16)h2f[2 * kb2 + 1][0]; Q.h[1] = (__bf16)h2f[2 * kb2 + 1][1];
            Q.h[2] = (__bf16)h2f[2 * kb2 + 1][2]; Q.h[3] = (__bf16)h2f[2 * kb2 + 1][3];
            const int px0 = __shfl(P.i2[0], sh0), qx0 = __shfl(Q.i2[0], sh0);
            const int py0 = __shfl(P.i2[1], sh0), qy0 = __shfl(Q.i2[1], sh0);
            const int px1 = __shfl(P.i2[0], sh1), qx1 = __shfl(Q.i2[0], sh1);
            const int py1 = __shfl(P.i2[1], sh1), qy1 = __shfl(Q.i2[1], sh1);
            union V { int ii[4]; bf16x8 vv; } R;
            R.ii[0] = rlo ? px0 : qx0;
            R.ii[1] = rlo ? py0 : qy0;
            R.ii[2] = rlo ? px1 : qx1;
            R.ii[3] = rlo ? py1 : qy1;
            b2[kb2] = R.vv;
        }

        // ====== P2: consume C0 @slot2; stage G0 -> slot1 ======
        PSYNC("4");                                    // drains C0; C1 in flight
        stage_half(gluv + 128 * NH, slot1, w, l);

        f32x4 fco[8];
        #pragma unroll
        for (int j = 0; j < 4; ++j) {
            f32x4 acc = zero4;
            const char* rp = slot2 + (j * 16 + l15) * 256;
            #pragma unroll
            for (int kb = 0; kb < 4; ++kb) {
                const bf16x8 wf = *(const bf16x8*)(rp + (((kb * 4 + lg) ^ l15) << 4));
                acc = __builtin_amdgcn_mfma_f32_16x16x32_bf16(wf, b2[kb], acc, 0, 0, 0);
            }
            const float4 gb = *(const float4*)(sm + 384 + j * 16 + lg * 4);
            acc[0] += gb.x; acc[1] += gb.y; acc[2] += gb.z; acc[3] += gb.w;
            fco[j] = acc;
        }

        // ====== P3: consume C1 @slot0; stage G1 -> slot2 ======
        PSYNC("4");
        stage_half(gluv + 192 * NH, slot2, w, l);

        #pragma unroll
        for (int j = 4; j < 8; ++j) {
            f32x4 acc = zero4;
            const char* rp = slot0 + ((j - 4) * 16 + l15) * 256;
            #pragma unroll
            for (int kb = 0; kb < 4; ++kb) {
                const bf16x8 wf = *(const bf16x8*)(rp + (((kb * 4 + lg) ^ l15) << 4));
                acc = __builtin_amdgcn_mfma_f32_16x16x32_bf16(wf, b2[kb], acc, 0, 0, 0);
            }
            const float4 gb = *(const float4*)(sm + 384 + j * 16 + lg * 4);
            acc[0] += gb.x; acc[1] += gb.y; acc[2] += gb.z; acc[3] += gb.w;
            fco[j] = acc;
        }

        // ====== P4: consume G0 @slot1; stage F0(vn) -> slot0 ======
        PSYNC("4");
        stage_half(fc2t + (size_t)vn * (NH * NH), slot0, w, l);

        f32x4 sv[8];
        #pragma unroll
        for (int j = 0; j < 4; ++j) {
            f32x4 acc = zero4;
            const char* rp = slot1 + (j * 16 + l15) * 256;
            #pragma unroll
            for (int kb = 0; kb < 4; ++kb) {
                const bf16x8 wg = *(const bf16x8*)(rp + (((kb * 4 + lg) ^ l15) << 4));
                acc = __builtin_amdgcn_mfma_f32_16x16x32_bf16(wg, b2[kb], acc, 0, 0, 0);
            }
            const float4 bga = *(const float4*)(sm + 512 + j * 16 + lg * 4);
            const float4 sw4 = *(const float4*)(sm + 640 + j * 16 + lg * 4);
            const float4 sb4 = *(const float4*)(sm + 768 + j * 16 + lg * 4);
            f32x4 s;
            s[0] = fmaf(xv, sw4.x, sb4.x) + fco[j][0] * sigm_f(acc[0] + bga.x);
            s[1] = fmaf(xv, sw4.y, sb4.y) + fco[j][1] * sigm_f(acc[1] + bga.y);
            s[2] = fmaf(xv, sw4.z, sb4.z) + fco[j][2] * sigm_f(acc[2] + bga.z);
            s[3] = fmaf(xv, sw4.w, sb4.w) + fco[j][3] * sigm_f(acc[3] + bga.w);
            sv[j] = s;
        }

        // ====== P5: consume G1 @slot2; stage smalls(vn) + F1(vn)->slot1 + x/w ======
        PSYNC("4");
        stage_smalls(smalls + (size_t)vn * 1024,
                     lds + SMS_OFF + ((i + 1) & 1) * SMS_BYTES, w, l);     // oldest of P5
        stage_half(fc2t + (size_t)vn * (NH * NH) + 64 * NH, slot1, w, l);  // F1'
        xn = xs[rowoff + vn];
        wn = wts[rowoff + vn];

        #pragma unroll
        for (int j = 4; j < 8; ++j) {
            f32x4 acc = zero4;
            const char* rp = slot2 + ((j - 4) * 16 + l15) * 256;
            #pragma unroll
            for (int kb = 0; kb < 4; ++kb) {
                const bf16x8 wg = *(const bf16x8*)(rp + (((kb * 4 + lg) ^ l15) << 4));
                acc = __builtin_amdgcn_mfma_f32_16x16x32_bf16(wg, b2[kb], acc, 0, 0, 0);
            }
            const float4 bga = *(const float4*)(sm + 512 + j * 16 + lg * 4);
            const float4 sw4 = *(const float4*)(sm + 640 + j * 16 + lg * 4);
            const float4 sb4 = *(const float4*)(sm + 768 + j * 16 + lg * 4);
            f32x4 s;
            s[0] = fmaf(xv, sw4.x, sb4.x) + fco[j][0] * sigm_f(acc[0] + bga.x);
            s[1] = fmaf(xv, sw4.y, sb4.y) + fco[j][1] * sigm_f(acc[1] + bga.y);
            s[2] = fmaf(xv, sw4.z, sb4.z) + fco[j][2] * sigm_f(acc[2] + bga.z);
            s[3] = fmaf(xv, sw4.w, sb4.w) + fco[j][3] * sigm_f(acc[3] + bga.w);
            sv[j] = s;
        }

        // ---- LN over 128 features of token l15 (own 32 + 4-lane cross-reduce)
        float t1 = 0.f, t2 = 0.f;
        #pragma unroll
        for (int j = 0; j < 8; ++j) {
            #pragma unroll
            for (int r = 0; r < 4; ++r) { t1 += sv[j][r]; t2 = fmaf(sv[j][r], sv[j][r], t2); }
        }
        t1 += __shfl_xor(t1, 16); t2 += __shfl_xor(t2, 16);
        t1 += __shfl_xor(t1, 32); t2 += __shfl_xor(t2, 32);
        const float mu  = t1 * (1.f / 128.f);
        const float var = t2 * (1.f / 128.f) - mu * mu;
        const float rsv = rsqrtf(fmaxf(var, 0.f) + 1e-5f);

        #pragma unroll
        for (int j = 0; j < 8; ++j) {
            const float4 lg4 = *(const float4*)(lnS + j * 16 + lg * 4);
            const float4 lb4 = *(const float4*)(lnS + 128 + j * 16 + lg * 4);
            const float y0 = fmaf((sv[j][0] - mu) * rsv, lg4.x, lb4.x);
            const float y1 = fmaf((sv[j][1] - mu) * rsv, lg4.y, lb4.y);
            const float y2 = fmaf((sv[j][2] - mu) * rsv, lg4.z, lb4.z);
            const float y3 = fmaf((sv[j][3] - mu) * rsv, lg4.w, lb4.w);
            acc_out[j][0] = fmaf(wv, y0, acc_out[j][0]);
            acc_out[j][1] = fmaf(wv, y1, acc_out[j][1]);
            acc_out[j][2] = fmaf(wv, y2, acc_out[j][2]);
            acc_out[j][3] = fmaf(wv, y3, acc_out[j][3]);
        }

        xv = xn; wv = wn;
    }

    asm volatile("s_waitcnt vmcnt(0)" ::: "memory");   // drain leftover DMA

    // ---- epilogue: atomics; 8 sharers per line, one per XCD (R12-proven) ----
    #pragma unroll
    for (int j = 0; j < 8; ++j) {
        #pragma unroll
        for (int r = 0; r < 4; ++r)
            atomicAdd(&out[(size_t)(m0 + l15) * NH + j * 16 + lg * 4 + r], acc_out[j][r]);
    }
}

extern "C" void kernel_launch(void* const* d_in, const int* in_sizes, int n_in,
                              void* d_out, int out_size, void* d_ws, size_t ws_size,
                              hipStream_t stream) {
    (void)in_sizes; (void)n_in; (void)out_size; (void)ws_size;

    const float* xs     = (const float*)d_in[0];
    const float* fc1_w  = (const float*)d_in[1];
    const float* fc1_b  = (const float*)d_in[2];
    const float* fc2_w  = (const float*)d_in[3];
    const float* fc2_b  = (const float*)d_in[4];
    const float* glu_w  = (const float*)d_in[5];
    const float* glu_b  = (const float*)d_in[6];
    const float* skip_w = (const float*)d_in[7];
    const float* skip_b = (const float*)d_in[8];
    const float* ln_g   = (const float*)d_in[9];
    const float* ln_b   = (const float*)d_in[10];
    const float* wfc1_w = (const float*)d_in[11];
    const float* wfc1_b = (const float*)d_in[12];
    const float* wfc2_w = (const float*)d_in[13];
    const float* wfc2_b = (const float*)d_in[14];
    const float* wglu_w = (const float*)d_in[15];
    const float* wglu_b = (const float*)d_in[16];
    const float* wln_g  = (const float*)d_in[17];
    const float* wln_b  = (const float*)d_in[18];

    float* out = (float*)d_out;
    float* wts = out + (size_t)NROWS * NH;

    __bf16* fc2t   = (__bf16*)d_ws;
    __bf16* glu16  = fc2t + (size_t)NV * NH * NH;
    float*  smalls = (float*)(glu16 + (size_t)NV * NG * NH);

    hipMemsetAsync(d_out, 0, (size_t)NROWS * NH * sizeof(float), stream);

    k_setup<<<NB_FC2 + NB_GLU + NB_SM + NB_WTS, 256, 0, stream>>>(
        fc2_w, fc2t, glu_w, glu16,
        fc1_w, fc1_b, fc2_b, glu_b, skip_w, skip_b, smalls,
        xs, wfc1_w, wfc1_b, wfc2_w, wfc2_b, wglu_w, wglu_b, wln_g, wln_b, wts);

    k_main<<<(NROWS / 64) * 8, 256, 0, stream>>>(xs, fc2t, glu16, smalls,
                                                 ln_g, ln_b, wts, out);
}